// Round 9
// baseline (106.481 us; speedup 1.0000x reference)
//
#include <hip/hip_runtime.h>
#include <hip/hip_fp16.h>

// Problem constants (from reference)
#define SPP   16
#define SH    256
#define SW    256
#define HI    1024
#define WI    1024
#define CH    3
#define BATCH 4

#define TS    8     // sensor tile = 8x8 px per WAVE, 1 px per lane, 16 spp in-lane
#define MAXD  46    // exact max bbox at t=1: floor-diff(8px*5.2517) + 4 = 46
#define NPAD  2176  // LDS px slots: 34 chunks-of-64 (pad region absorbs clamped iters)
#define NTHR  64    // one wave per block

// tanh via v_exp_f32; |arg| <= ~1.2 here, abs error ~1e-6 (threshold 1.7e-2).
__device__ __forceinline__ float fast_tanh(float x) {
    const float e = __expf(2.0f * x);
    return (e - 1.0f) * __builtin_amdgcn_rcpf(e + 1.0f);
}

// R8 post-mortem: clean wave-sync structure at 6 waves/CU (f32 LDS 26KB/wave)
// still ~34us; every latency class exposed at 1.5 waves/SIMD. This round
// doubles residency: planar fp16 LDS (half2 RG + half B = 6 B/px, 13.1 KB
// per wave) -> 12 waves/CU. fp16 requires reg-staging (load->cvt->ds_write);
// to avoid R6's serial per-iteration latency this is software-pipelined two
// chunks deep with NAMED A/B register sets — the compiler emits counted
// vmcnt waits between sets (T4 at source level). All R8 wins retained:
// 1 px/lane, 16 in-lane spp (coalesced jitter, no shuffles), no barriers.
__global__ __launch_bounds__(NTHR, 3) void foveated_hocc8(
    const float* __restrict__ img,
    const float* __restrict__ t_ptr,
    const float* __restrict__ jitter,
    float* __restrict__ out)
{
    __shared__ __half2 RG[NPAD];   // 8704 B
    __shared__ __half  B [NPAD];   // 4352 B   -> 13056 B total, 12 blocks/CU

    // XCD slab swizzle: 4096 blocks -> each XCD gets 512 contiguous logical
    // blocks (contiguous sensor rows -> overlapping bboxes stay in one L2).
    const int bid  = blockIdx.x;
    const int L    = (bid & 7) * 512 + (bid >> 3);
    const int b    = L >> 10;            // 1024 tiles per batch (32x32 of 8x8)
    const int rem  = L & 1023;
    const int trow = rem >> 5;
    const int tcol = rem & 31;
    const int sx0  = tcol * TS;
    const int sy0  = trow * TS;

    const int lane = threadIdx.x;        // 0..63
    const int sx   = sx0 + (lane & 7);
    const int sy   = sy0 + (lane >> 3);

    const float step  = 2.0f / 256.0f;
    const float tt    = t_ptr[0];
    const float inv_s = __builtin_amdgcn_rcpf(fast_tanh(tt));

    // Uniform bbox of this wave's tile (warp is monotone/separable for t>0).
    auto gmap = [&](float p) {
        float g = (fast_tanh(tt * p) * inv_s + 1.0f) * 512.0f - 0.5f;
        return fminf(fmaxf(g, 0.0f), 1023.0f);
    };
    const float pxmin = -1.0f + sx0 * step, pxmax = pxmin + TS * step;
    const float pymin = -1.0f + sy0 * step, pymax = pymin + TS * step;
    const int x_lo = max((int)gmap(pxmin) - 1, 0);
    const int x_hi = min((int)gmap(pxmax) + 2, WI - 1);
    const int y_lo = max((int)gmap(pymin) - 1, 0);
    const int y_hi = min((int)gmap(pymax) + 2, HI - 1);
    const int ncols = x_hi - x_lo + 1;
    const int nrows = y_hi - y_lo + 1;
    const bool fits = (ncols > 0) && (nrows > 0) &&
                      (ncols <= MAXD) && (nrows <= MAXD);  // always true at t=1

    const size_t plane = (size_t)HI * WI;
    const float* __restrict__ p0 = img + (size_t)(b * CH) * plane;
    const float* __restrict__ p1 = p0 + plane;
    const float* __restrict__ p2 = p1 + plane;

    const float px = -1.0f + sx * step;
    const float py = -1.0f + sy * step;

    // ---- Issue ALL 16 jitter loads first (coalesced rows; named registers,
    // static consumers -> VGPRs). Their latency hides under staging. ----
    const float2* __restrict__ jit2 = (const float2*)jitter;
    const int jbase = sy * SW + sx;
    const float2 jv0  = jit2[jbase +  0 * (SH * SW)];
    const float2 jv1  = jit2[jbase +  1 * (SH * SW)];
    const float2 jv2  = jit2[jbase +  2 * (SH * SW)];
    const float2 jv3  = jit2[jbase +  3 * (SH * SW)];
    const float2 jv4  = jit2[jbase +  4 * (SH * SW)];
    const float2 jv5  = jit2[jbase +  5 * (SH * SW)];
    const float2 jv6  = jit2[jbase +  6 * (SH * SW)];
    const float2 jv7  = jit2[jbase +  7 * (SH * SW)];
    const float2 jv8  = jit2[jbase +  8 * (SH * SW)];
    const float2 jv9  = jit2[jbase +  9 * (SH * SW)];
    const float2 jv10 = jit2[jbase + 10 * (SH * SW)];
    const float2 jv11 = jit2[jbase + 11 * (SH * SW)];
    const float2 jv12 = jit2[jbase + 12 * (SH * SW)];
    const float2 jv13 = jit2[jbase + 13 * (SH * SW)];
    const float2 jv14 = jit2[jbase + 14 * (SH * SW)];
    const float2 jv15 = jit2[jbase + 15 * (SH * SW)];

    float acc0 = 0.0f, acc1 = 0.0f, acc2 = 0.0f, dsum = 0.0f;

    auto sample_lds = [&](float jx, float jy) {
        const float posx = px + jx * step;
        const float posy = py + jy * step;

        const float thx = fast_tanh(tt * posx);
        const float thy = fast_tanh(tt * posy);
        const float ddx = tt * (1.0f - thx * thx) * inv_s;
        const float ddy = tt * (1.0f - thy * thy) * inv_s;
        const float det = ddx * ddy;

        float gx = (thx * inv_s + 1.0f) * 512.0f - 0.5f;
        float gy = (thy * inv_s + 1.0f) * 512.0f - 0.5f;
        gx = fminf(fmaxf(gx, 0.0f), (float)(WI - 1));
        gy = fminf(fmaxf(gy, 0.0f), (float)(HI - 1));

        const int xb = min((int)gx, WI - 2);
        const int yb = min((int)gy, HI - 2);
        const float fx = gx - (float)xb;
        const float fy = gy - (float)yb;

        const float w00 = (1.0f - fx) * (1.0f - fy) * det;
        const float w01 = fx * (1.0f - fy) * det;
        const float w10 = (1.0f - fx) * fy * det;
        const float w11 = fx * fy * det;
        dsum += det;

        // Packed planar layout: LDS index = row*ncols + col.
        const int lidx = (yb - y_lo) * ncols + (xb - x_lo);
        const int l10  = lidx + ncols;

        const float2 f00 = __half22float2(RG[lidx]);
        const float2 f01 = __half22float2(RG[lidx + 1]);
        const float2 f10 = __half22float2(RG[l10]);
        const float2 f11 = __half22float2(RG[l10 + 1]);
        const float v00 = __half2float(B[lidx]);
        const float v01 = __half2float(B[lidx + 1]);
        const float v10 = __half2float(B[l10]);
        const float v11 = __half2float(B[l10 + 1]);

        acc0 += w00 * f00.x + w01 * f01.x + w10 * f10.x + w11 * f11.x;
        acc1 += w00 * f00.y + w01 * f01.y + w10 * f10.y + w11 * f11.y;
        acc2 += w00 * v00   + w01 * v01   + w10 * v10   + w11 * v11;
    };

    auto sample_glb = [&](float jx, float jy) {
        const float posx = px + jx * step;
        const float posy = py + jy * step;

        const float thx = fast_tanh(tt * posx);
        const float thy = fast_tanh(tt * posy);
        const float ddx = tt * (1.0f - thx * thx) * inv_s;
        const float ddy = tt * (1.0f - thy * thy) * inv_s;
        const float det = ddx * ddy;

        float gx = (thx * inv_s + 1.0f) * 512.0f - 0.5f;
        float gy = (thy * inv_s + 1.0f) * 512.0f - 0.5f;
        gx = fminf(fmaxf(gx, 0.0f), (float)(WI - 1));
        gy = fminf(fmaxf(gy, 0.0f), (float)(HI - 1));

        const int xb = min((int)gx, WI - 2);
        const int yb = min((int)gy, HI - 2);
        const float fx = gx - (float)xb;
        const float fy = gy - (float)yb;

        const float w00 = (1.0f - fx) * (1.0f - fy) * det;
        const float w01 = fx * (1.0f - fy) * det;
        const float w10 = (1.0f - fx) * fy * det;
        const float w11 = fx * fy * det;
        dsum += det;

        const int i0 = yb * WI + xb;
        const int i1 = i0 + WI;
        { const float a0 = p0[i0], a1 = p0[i0 + 1], c0 = p0[i1], c1 = p0[i1 + 1];
          acc0 += a0 * w00 + a1 * w01 + c0 * w10 + c1 * w11; }
        { const float a0 = p1[i0], a1 = p1[i0 + 1], c0 = p1[i1], c1 = p1[i1 + 1];
          acc1 += a0 * w00 + a1 * w01 + c0 * w10 + c1 * w11; }
        { const float a0 = p2[i0], a1 = p2[i0 + 1], c0 = p2[i1], c1 = p2[i1 + 1];
          acc2 += a0 * w00 + a1 * w01 + c0 * w10 + c1 * w11; }
    };

    if (fits) {
        const int npix  = nrows * ncols;
        const int niter = (npix + 63) >> 6;                      // <= 34
        const unsigned mdiv = (1u << 22) / (unsigned)ncols + 1u; // i<4096: exact

        // Chunked reg-staged pipeline: chunks of 8 iters (iters 0..33 across
        // chunks {8,8,8,8,2}). ISSUE loads a chunk into a NAMED register set;
        // COMMIT converts+writes it to LDS. A/B alternation is 2-deep: the
        // compiler inserts counted vmcnt between sets, so chunk k+1's HBM
        // latency hides under chunk k's convert+write. Global index is
        // clamped (dup loads hit cache); LDS index is UNclamped (unique slot
        // in the NPAD pad region -> no same-address write serialization).
        float arA[8], agA[8], abA[8];
        float arB[8], agB[8], abB[8];

        #define ISSUE(K, CNT, VR, VG, VB)                                   \
            if ((K) * 8 < niter) {                                          \
                _Pragma("unroll")                                           \
                for (int u = 0; u < (CNT); ++u) {                           \
                    const int it = (K) * 8 + u;                             \
                    const int ic = min(it * 64 + lane, npix - 1);           \
                    const int rr = (int)(((unsigned)ic * mdiv) >> 22);      \
                    const int cc = ic - rr * ncols;                         \
                    const int g  = (y_lo + rr) * WI + (x_lo + cc);          \
                    VR[u] = p0[g];                                          \
                    VG[u] = p1[g];                                          \
                    VB[u] = p2[g];                                          \
                }                                                           \
            }

        #define COMMIT(K, CNT, VR, VG, VB)                                  \
            if ((K) * 8 < niter) {                                          \
                _Pragma("unroll")                                           \
                for (int u = 0; u < (CNT); ++u) {                           \
                    const int i = ((K) * 8 + u) * 64 + lane;                \
                    RG[i] = __floats2half2_rn(VR[u], VG[u]);                \
                    B [i] = __float2half_rn(VB[u]);                         \
                }                                                           \
            }

        ISSUE (0, 8, arA, agA, abA);
        ISSUE (1, 8, arB, agB, abB);
        COMMIT(0, 8, arA, agA, abA);
        ISSUE (2, 8, arA, agA, abA);
        COMMIT(1, 8, arB, agB, abB);
        ISSUE (3, 8, arB, agB, abB);
        COMMIT(2, 8, arA, agA, abA);
        ISSUE (4, 2, arA, agA, abA);
        COMMIT(3, 8, arB, agB, abB);
        COMMIT(4, 2, arA, agA, abA);

        #undef ISSUE
        #undef COMMIT

        // Same wave produced and consumes: drain LDS writes, no barrier.
        asm volatile("s_waitcnt lgkmcnt(0)" ::: "memory");
        __builtin_amdgcn_sched_barrier(0);

        // ---- This lane's 16 spp from LDS (fully unrolled, independent chains) ----
        sample_lds(jv0.x,  jv0.y);   sample_lds(jv1.x,  jv1.y);
        sample_lds(jv2.x,  jv2.y);   sample_lds(jv3.x,  jv3.y);
        sample_lds(jv4.x,  jv4.y);   sample_lds(jv5.x,  jv5.y);
        sample_lds(jv6.x,  jv6.y);   sample_lds(jv7.x,  jv7.y);
        sample_lds(jv8.x,  jv8.y);   sample_lds(jv9.x,  jv9.y);
        sample_lds(jv10.x, jv10.y);  sample_lds(jv11.x, jv11.y);
        sample_lds(jv12.x, jv12.y);  sample_lds(jv13.x, jv13.y);
        sample_lds(jv14.x, jv14.y);  sample_lds(jv15.x, jv15.y);
    } else {
        // ---- Fallback: direct global gathers (never taken at t=1) ----
        sample_glb(jv0.x,  jv0.y);   sample_glb(jv1.x,  jv1.y);
        sample_glb(jv2.x,  jv2.y);   sample_glb(jv3.x,  jv3.y);
        sample_glb(jv4.x,  jv4.y);   sample_glb(jv5.x,  jv5.y);
        sample_glb(jv6.x,  jv6.y);   sample_glb(jv7.x,  jv7.y);
        sample_glb(jv8.x,  jv8.y);   sample_glb(jv9.x,  jv9.y);
        sample_glb(jv10.x, jv10.y);  sample_glb(jv11.x, jv11.y);
        sample_glb(jv12.x, jv12.y);  sample_glb(jv13.x, jv13.y);
        sample_glb(jv14.x, jv14.y);  sample_glb(jv15.x, jv15.y);
    }

    // ---- 1 px per lane: no reduction, contiguous stores ----
    const float inv_d = 1.0f / dsum;
    const int pix = sy * SW + sx;
    const size_t ob = (size_t)b * CH * (SH * SW) + pix;
    out[ob]                 = acc0 * inv_d;
    out[ob + (SH * SW)]     = acc1 * inv_d;
    out[ob + 2 * (SH * SW)] = acc2 * inv_d;
}

extern "C" void kernel_launch(void* const* d_in, const int* in_sizes, int n_in,
                              void* d_out, int out_size, void* d_ws, size_t ws_size,
                              hipStream_t stream) {
    const float* img    = (const float*)d_in[0];
    const float* t      = (const float*)d_in[1];
    const float* jitter = (const float*)d_in[2];
    float* out          = (float*)d_out;

    // 4 batches x 32x32 tiles of 8x8 px = 4096 blocks, 64 threads (1 wave)
    hipLaunchKernelGGL(foveated_hocc8, dim3(4096), dim3(NTHR), 0, stream,
                       img, t, jitter, out);
}